// Round 3
// baseline (2905.478 us; speedup 1.0000x reference)
//
#include <hip/hip_runtime.h>
#include <cstdint>
#include <cstddef>

#define Bsz 512
#define Tsz 512
#define Isz 64
#define Hsz 256

typedef _Float16 f16;
typedef _Float16 half8_t __attribute__((ext_vector_type(8)));
typedef float float4_t __attribute__((ext_vector_type(4)));

__device__ __forceinline__ void async_ld16(const void* g, void* lds) {
  __builtin_amdgcn_global_load_lds(
      (const __attribute__((address_space(1))) void*)g,
      (__attribute__((address_space(3))) void*)lds, 16, 0, 0);
}

// ---------------- layer 0: input is f32 x [B, Tsz, 64], register-prefetched ----------------
__global__ __launch_bounds__(256, 1)
void rnn_layer0_kernel(const float* __restrict__ x, const float* __restrict__ w_ih,
                       const float* __restrict__ w_hh, const float* __restrict__ b_ih,
                       const float* __restrict__ b_hh, f16* __restrict__ out,
                       const f16* __restrict__ st_in, f16* __restrict__ st_out,
                       int TC, int c0, int first)
{
  __shared__ __align__(16) char h_lds[8192];   // h state [32 chunks][16 rows][16B]
  const int tid  = threadIdx.x;
  const int lane = tid & 63;
  const int wave = tid >> 6;
  const int m    = lane & 15;
  const int q    = lane >> 4;
  const int b0   = blockIdx.x * 16;

  // register-resident weights (B-operand: B[k][n]=W[n][k], n=lane&15, k=q*8+i)
  half8_t whh[4][8], wih[4][2];
  float bias[4];
#pragma unroll
  for (int jt = 0; jt < 4; ++jt) {
    const int j = wave * 64 + jt * 16 + m;
    bias[jt] = b_ih[j] + b_hh[j];
#pragma unroll
    for (int c = 0; c < 8; ++c) {
      const float* wp = w_hh + j * 256 + c * 32 + q * 8;
#pragma unroll
      for (int i = 0; i < 8; ++i) whh[jt][c][i] = (f16)wp[i];
    }
#pragma unroll
    for (int c = 0; c < 2; ++c) {
      const float* wp = w_ih + j * 64 + c * 32 + q * 8;
#pragma unroll
      for (int i = 0; i < 8; ++i) wih[jt][c][i] = (f16)wp[i];
    }
  }

  // h init: zeros on first chunk, else reload carried state
  if (first) {
    for (int i = tid; i < 2048; i += 256) ((int*)h_lds)[i] = 0;
  } else {
#pragma unroll
    for (int jt = 0; jt < 4; ++jt) {
      const int j = wave * 64 + jt * 16 + m;
#pragma unroll
      for (int r = 0; r < 4; ++r) {
        const int b = q * 4 + r;
        const f16 hv = st_in[(size_t)(b0 + b) * 256 + j];
        *(f16*)(h_lds + (j >> 3) * 256 + b * 16 + (j & 7) * 2) = hv;
      }
    }
  }
  asm volatile("s_waitcnt lgkmcnt(0)\n\ts_barrier" ::: "memory");

  // x register prefetch, 2 deep: slot holds 4 float4 = x[b0+m][t][c*32+q*8 .. +7], c=0,1
  float4_t xp[2][4];
  auto xload = [&](int tg, float4_t* d) {
    const float* base = x + ((size_t)(b0 + m) * Tsz + tg) * 64 + q * 8;
    d[0] = *(const float4_t*)(base);
    d[1] = *(const float4_t*)(base + 4);
    d[2] = *(const float4_t*)(base + 32);
    d[3] = *(const float4_t*)(base + 36);
  };
  xload(c0, xp[0]);
  xload(c0 + 1, xp[1]);

  const int lo = m * 16;
  for (int tl = 0; tl < TC; ++tl) {
    // build fragments
    half8_t xf[2];
#pragma unroll
    for (int c = 0; c < 2; ++c)
#pragma unroll
      for (int u = 0; u < 8; ++u) xf[c][u] = (f16)xp[tl & 1][c * 2 + (u >> 2)][u & 3];
    half8_t hf[8];
#pragma unroll
    for (int c = 0; c < 8; ++c)
      hf[c] = *(const half8_t*)(h_lds + (c * 4 + q) * 256 + lo);

    asm volatile("s_waitcnt lgkmcnt(0)\n\ts_barrier" ::: "memory");  // reads done

    float4_t acc[4];
#pragma unroll
    for (int jt = 0; jt < 4; ++jt) {
      float4_t a = {bias[jt], bias[jt], bias[jt], bias[jt]};
#pragma unroll
      for (int c = 0; c < 2; ++c)
        a = __builtin_amdgcn_mfma_f32_16x16x32_f16(xf[c], wih[jt][c], a, 0, 0, 0);
#pragma unroll
      for (int c = 0; c < 8; ++c)
        a = __builtin_amdgcn_mfma_f32_16x16x32_f16(hf[c], whh[jt][c], a, 0, 0, 0);
      acc[jt] = a;
    }

    // epilogue: tanh; C/D layout col=lane&15, row=q*4+r
#pragma unroll
    for (int jt = 0; jt < 4; ++jt) {
      const int j = wave * 64 + jt * 16 + m;
#pragma unroll
      for (int r = 0; r < 4; ++r) {
        const float e    = exp2f(acc[jt][r] * 2.8853900817779268f);
        const float hval = 1.0f - 2.0f * __builtin_amdgcn_rcpf(1.0f + e);
        const f16 hv = (f16)hval;
        const int b = q * 4 + r;
        *(f16*)(h_lds + (j >> 3) * 256 + b * 16 + (j & 7) * 2) = hv;
        out[((size_t)(b0 + b) * TC + tl) * 256 + j] = hv;
      }
    }

    // prefetch x for tl+2 into the just-consumed slot
    int tn = tl + 2; if (tn >= TC) tn = TC - 1;
    xload(c0 + tn, xp[tl & 1]);

    asm volatile("s_waitcnt lgkmcnt(0)\n\ts_barrier" ::: "memory");  // h writes visible
  }

  // persist h state
#pragma unroll
  for (int jt = 0; jt < 4; ++jt) {
    const int j = wave * 64 + jt * 16 + m;
#pragma unroll
    for (int r = 0; r < 4; ++r) {
      const int b = q * 4 + r;
      st_out[(size_t)(b0 + b) * 256 + j] = *(const f16*)(h_lds + (j >> 3) * 256 + b * 16 + (j & 7) * 2);
    }
  }
}

// ---------------- layers 1,2: input f16 [B, TC, 256], LDS-staged via global_load_lds ----------------
__global__ __launch_bounds__(256, 1)
void rnn_layer_kernel(const f16* __restrict__ in, const float* __restrict__ w_ih,
                      const float* __restrict__ w_hh, const float* __restrict__ b_ih,
                      const float* __restrict__ b_hh, f16* __restrict__ out,
                      const f16* __restrict__ st_in, f16* __restrict__ st_out,
                      int TC, int first)
{
  __shared__ __align__(16) char smem[8192 + 3 * 8192];
  char* h_lds = smem;
  char* stage = smem + 8192;           // 3-deep ring, [32 chunks][16 rows][16B] each

  const int tid  = threadIdx.x;
  const int lane = tid & 63;
  const int wave = tid >> 6;
  const int m    = lane & 15;
  const int q    = lane >> 4;
  const int b0   = blockIdx.x * 16;

  half8_t whh[4][8], wih[4][8];
  float bias[4];
#pragma unroll
  for (int jt = 0; jt < 4; ++jt) {
    const int j = wave * 64 + jt * 16 + m;
    bias[jt] = b_ih[j] + b_hh[j];
#pragma unroll
    for (int c = 0; c < 8; ++c) {
      const float* wp = w_hh + j * 256 + c * 32 + q * 8;
#pragma unroll
      for (int i = 0; i < 8; ++i) whh[jt][c][i] = (f16)wp[i];
    }
#pragma unroll
    for (int c = 0; c < 8; ++c) {
      const float* wp = w_ih + j * 256 + c * 32 + q * 8;
#pragma unroll
      for (int i = 0; i < 8; ++i) wih[jt][c][i] = (f16)wp[i];
    }
  }

  if (first) {
    for (int i = tid; i < 2048; i += 256) ((int*)h_lds)[i] = 0;
  } else {
#pragma unroll
    for (int jt = 0; jt < 4; ++jt) {
      const int j = wave * 64 + jt * 16 + m;
#pragma unroll
      for (int r = 0; r < 4; ++r) {
        const int b = q * 4 + r;
        const f16 hv = st_in[(size_t)(b0 + b) * 256 + j];
        *(f16*)(h_lds + (j >> 3) * 256 + b * 16 + (j & 7) * 2) = hv;
      }
    }
  }

  // stage in[b0:b0+16, tl, :] into ring buffer buf (8 async calls; 2 per wave)
  auto issue_stage = [&](int tl, int buf) {
    char* lb = stage + buf * 8192;
#pragma unroll
    for (int k = 0; k < 2; ++k) {
      const int cb = wave * 2 + k;
      const int c  = cb * 4 + q;       // chunk 0..31
      const char* g = (const char*)in + ((size_t)(b0 + m) * TC + tl) * 512 + c * 16;
      async_ld16(g, lb + cb * 1024);   // hw dst = base + lane*16
    }
  };

  issue_stage(0, 0);
  issue_stage(1, 1);
  // stage(0) complete (2 newest = stage(1) in flight); lgkm covers h_lds init
  asm volatile("s_waitcnt vmcnt(2) lgkmcnt(0)\n\ts_barrier" ::: "memory");

  const int lo = m * 16;
  for (int tl = 0; tl < TC; ++tl) {
    const char* sb = stage + (tl % 3) * 8192;

    half8_t hf[8], xf[8];
#pragma unroll
    for (int c = 0; c < 8; ++c)
      hf[c] = *(const half8_t*)(h_lds + (c * 4 + q) * 256 + lo);
#pragma unroll
    for (int c = 0; c < 8; ++c)
      xf[c] = *(const half8_t*)(sb + (c * 4 + q) * 256 + lo);

    asm volatile("s_waitcnt lgkmcnt(0)\n\ts_barrier" ::: "memory");  // reads done

    float4_t acc[4];
#pragma unroll
    for (int jt = 0; jt < 4; ++jt) {
      float4_t a = {bias[jt], bias[jt], bias[jt], bias[jt]};
#pragma unroll
      for (int c = 0; c < 8; ++c)
        a = __builtin_amdgcn_mfma_f32_16x16x32_f16(xf[c], wih[jt][c], a, 0, 0, 0);
#pragma unroll
      for (int c = 0; c < 8; ++c)
        a = __builtin_amdgcn_mfma_f32_16x16x32_f16(hf[c], whh[jt][c], a, 0, 0, 0);
      acc[jt] = a;
    }

#pragma unroll
    for (int jt = 0; jt < 4; ++jt) {
      const int j = wave * 64 + jt * 16 + m;
#pragma unroll
      for (int r = 0; r < 4; ++r) {
        const float e    = exp2f(acc[jt][r] * 2.8853900817779268f);
        const float hval = 1.0f - 2.0f * __builtin_amdgcn_rcpf(1.0f + e);
        const f16 hv = (f16)hval;
        const int b = q * 4 + r;
        *(f16*)(h_lds + (j >> 3) * 256 + b * 16 + (j & 7) * 2) = hv;
        out[((size_t)(b0 + b) * TC + tl) * 256 + j] = hv;
      }
    }

    int tn = tl + 2; if (tn >= TC) tn = TC - 1;   // tail dup, buffer never read
    issue_stage(tn, (tl + 2) % 3);
    // 18 newest vm-ops (16 stores + 2 stage calls) may stay in flight;
    // everything older (incl. stage(tl+1)) is complete.
    asm volatile("s_waitcnt vmcnt(18) lgkmcnt(0)\n\ts_barrier" ::: "memory");
  }

#pragma unroll
  for (int jt = 0; jt < 4; ++jt) {
    const int j = wave * 64 + jt * 16 + m;
#pragma unroll
    for (int r = 0; r < 4; ++r) {
      const int b = q * 4 + r;
      st_out[(size_t)(b0 + b) * 256 + j] = *(const f16*)(h_lds + (j >> 3) * 256 + b * 16 + (j & 7) * 2);
    }
  }
}

__global__ void fc_kernel(const f16* __restrict__ h, const float* __restrict__ w_fc,
                          const float* __restrict__ b_fc, float* __restrict__ outp) {
  const int b = blockIdx.x;
  const int lane = threadIdx.x;  // 64
  const f16* hp = h + (size_t)b * 256 + lane * 4;
  f16 h0 = hp[0], h1 = hp[1], h2 = hp[2], h3 = hp[3];
  const float4_t w = *(const float4_t*)(w_fc + lane * 4);
  float s = (float)h0 * w[0] + (float)h1 * w[1] + (float)h2 * w[2] + (float)h3 * w[3];
#pragma unroll
  for (int off = 32; off > 0; off >>= 1) s += __shfl_down(s, off, 64);
  if (lane == 0) outp[b] = s + b_fc[0];
}

extern "C" void kernel_launch(void* const* d_in, const int* in_sizes, int n_in,
                              void* d_out, int out_size, void* d_ws, size_t ws_size,
                              hipStream_t stream) {
  const float* x     = (const float*)d_in[0];
  const float* w_ih0 = (const float*)d_in[1];
  const float* w_hh0 = (const float*)d_in[2];
  const float* b_ih0 = (const float*)d_in[3];
  const float* b_hh0 = (const float*)d_in[4];
  const float* w_ih1 = (const float*)d_in[5];
  const float* w_hh1 = (const float*)d_in[6];
  const float* b_ih1 = (const float*)d_in[7];
  const float* b_hh1 = (const float*)d_in[8];
  const float* w_ih2 = (const float*)d_in[9];
  const float* w_hh2 = (const float*)d_in[10];
  const float* b_ih2 = (const float*)d_in[11];
  const float* b_hh2 = (const float*)d_in[12];
  const float* w_fc  = (const float*)d_in[13];
  const float* b_fc  = (const float*)d_in[14];

  // workspace layout: 3 h-states (256 KB each) + 2 chunk ping-pong buffers.
  // TC chosen from ws_size (constant across calls -> graph-safe).
  int TC = 16;
  const int cands[5] = {512, 256, 128, 64, 32};
  for (int i = 0; i < 5; ++i) {
    const size_t need = (size_t)1048576 + 2ull * (size_t)cands[i] * 262144ull;
    if (need <= ws_size) { TC = cands[i]; break; }
  }
  const int nch = Tsz / TC;

  char* ws = (char*)d_ws;
  f16* st0  = (f16*)(ws);
  f16* st1  = (f16*)(ws + 262144);
  f16* st2  = (f16*)(ws + 524288);
  f16* bufA = (f16*)(ws + 1048576);
  f16* bufB = (f16*)(ws + 1048576 + (size_t)TC * 262144);

  for (int c = 0; c < nch; ++c) {
    const int c0 = c * TC, first = (c == 0);
    rnn_layer0_kernel<<<32, 256, 0, stream>>>(x, w_ih0, w_hh0, b_ih0, b_hh0,
                                              bufA, st0, st0, TC, c0, first);
    rnn_layer_kernel<<<32, 256, 0, stream>>>(bufA, w_ih1, w_hh1, b_ih1, b_hh1,
                                             bufB, st1, st1, TC, first);
    rnn_layer_kernel<<<32, 256, 0, stream>>>(bufB, w_ih2, w_hh2, b_ih2, b_hh2,
                                             bufA, st2, st2, TC, first);
  }
  fc_kernel<<<512, 64, 0, stream>>>(st2, w_fc, b_fc, (float*)d_out);
}

// Round 5
// 1874.478 us; speedup vs baseline: 1.5500x; 1.5500x over previous
//
#include <hip/hip_runtime.h>
#include <cstdint>
#include <cstddef>

#define Tsz 512
#define TC  32          // steps per chunk
#define NCH 16          // Tsz / TC

typedef _Float16 f16;
typedef _Float16 half8_t __attribute__((ext_vector_type(8)));
typedef _Float16 half4_t __attribute__((ext_vector_type(4)));
typedef float float4_t __attribute__((ext_vector_type(4)));

__device__ __forceinline__ void async_ld16(const void* g, void* lds) {
  __builtin_amdgcn_global_load_lds(
      (const __attribute__((address_space(1))) void*)g,
      (__attribute__((address_space(3))) void*)lds, 16, 0, 0);
}

// One layer-chunk: TC steps of layer LAYER on one 16-row batch tile.
// 512 threads = 8 waves; wave owns 32 output cols (2 MFMA col-tiles).
// h double-buffered in LDS -> ONE __syncthreads per step (compiler-managed waits).
// Cross-layer handoff happens at kernel-launch boundaries (proven-coherent).
template<int LAYER>
__device__ __forceinline__ void layer_body(
    char* const smem, const int chunk, const int tile,
    const float* __restrict__ x,     // LAYER==0 input
    const f16* inbuf,                // LAYER>=1 input ring (image layout)
    const f16* __restrict__ wih_h, const f16* __restrict__ whh_h,
    const float* __restrict__ biasc,
    f16* outbuf,                     // LAYER<2 output ring (image layout)
    f16* st)                         // per-layer carried h (image layout)
{
  constexpr int NIN = (LAYER == 0) ? 2 : 8;
  char* const h_lds = smem;          // 2 x 8192: [32 chunks][16 rows][16B] images
  char* const stage = smem + 16384;  // 3 x 8192 input ring (same image layout)

  const int tid  = threadIdx.x;
  const int lane = tid & 63;
  const int wave = tid >> 6;
  const int m    = lane & 15;
  const int q    = lane >> 4;
  const int lo   = m * 16;
  const int t0   = chunk * TC;
  const int slot = chunk & 1;        // ring slot for both in (this layer) & out

  // register-resident f16 weights (B-operand: B[k][n]=W[n][k], n=lane&15, k=q*8+i)
  half8_t whh[2][8], wih[2][NIN];
  float bias[2];
#pragma unroll
  for (int jt = 0; jt < 2; ++jt) {
    const int j = wave * 32 + jt * 16 + m;
    bias[jt] = biasc[LAYER * 256 + j];
#pragma unroll
    for (int c = 0; c < 8; ++c)
      whh[jt][c] = *(const half8_t*)(whh_h + j * 256 + c * 32 + q * 8);
#pragma unroll
    for (int c = 0; c < NIN; ++c)
      wih[jt][c] = *(const half8_t*)(wih_h + j * (NIN * 32) + c * 32 + q * 8);
  }

  // h_{t0-1}: zeros on chunk 0, else carried state (image copy)
  if (chunk == 0)
    *(float4_t*)(h_lds + tid * 16) = float4_t{0.f, 0.f, 0.f, 0.f};
  else
    *(float4_t*)(h_lds + tid * 16) = *(const float4_t*)((const char*)st + tile * 8192 + tid * 16);

  // input machinery
  float4_t xp[3][4];                 // LAYER0: 3-deep register ring of f32 x rows
  auto xload = [&](int t, float4_t* d) {
    const int tc = (t > Tsz - 1) ? (Tsz - 1) : t;
    const float* base = x + ((size_t)(tile * 16 + m) * Tsz + tc) * 64 + q * 8;
    d[0] = *(const float4_t*)base;        d[1] = *(const float4_t*)(base + 4);
    d[2] = *(const float4_t*)(base + 32); d[3] = *(const float4_t*)(base + 36);
  };
  auto issue_stage = [&](int tl, int sl) {  // 8KB image; wave w covers bytes [w*1024, +1024)
    const char* g = (const char*)inbuf + (((size_t)(tile * 2 + slot) * TC + tl) << 13)
                    + wave * 1024 + lane * 16;
    async_ld16(g, stage + sl * 8192 + wave * 1024);
  };

  if constexpr (LAYER == 0) { xload(t0, xp[0]); xload(t0 + 1, xp[1]); xload(t0 + 2, xp[2]); }
  else                      { issue_stage(0, 0); issue_stage(1, 1); }
  __syncthreads();                   // h image + staged inputs all visible

  for (int tl = 0; tl < TC; ++tl) {
    char* cur = h_lds + (tl & 1) * 8192;
    char* nxt = h_lds + ((tl + 1) & 1) * 8192;

    // A-fragments + prefetch next input
    half8_t xf[NIN];
    if constexpr (LAYER == 0) {
      const float4_t* xr = xp[tl % 3];
#pragma unroll
      for (int c = 0; c < 2; ++c)
#pragma unroll
        for (int u = 0; u < 8; ++u) xf[c][u] = (f16)xr[c * 2 + (u >> 2)][u & 3];
      xload(t0 + tl + 3, xp[tl % 3]);          // overwrite just-consumed slot
    } else {
      const char* sb = stage + (tl % 3) * 8192;
#pragma unroll
      for (int c = 0; c < 8; ++c) xf[c] = *(const half8_t*)(sb + (c * 4 + q) * 256 + lo);
      if (tl + 2 < TC) issue_stage(tl + 2, (tl + 2) % 3);   // slot consumed last step
    }
    half8_t hf[8];
#pragma unroll
    for (int c = 0; c < 8; ++c) hf[c] = *(const half8_t*)(cur + (c * 4 + q) * 256 + lo);

    // two independent MFMA chains per col-tile
    float4_t acc[2];
#pragma unroll
    for (int jt = 0; jt < 2; ++jt) {
      float4_t a0 = {bias[jt], bias[jt], bias[jt], bias[jt]};
      float4_t a1 = {0.f, 0.f, 0.f, 0.f};
#pragma unroll
      for (int c = 0; c < NIN; ++c)
        a0 = __builtin_amdgcn_mfma_f32_16x16x32_f16(xf[c], wih[jt][c], a0, 0, 0, 0);
#pragma unroll
      for (int c = 0; c < 8; ++c)
        a1 = __builtin_amdgcn_mfma_f32_16x16x32_f16(hf[c], whh[jt][c], a1, 0, 0, 0);
      acc[jt] = a0 + a1;
    }

    // epilogue: tanh -> h(t) image in nxt. C/D layout: col=lane&15, row=q*4+r.
#pragma unroll
    for (int jt = 0; jt < 2; ++jt) {
      const int j = wave * 32 + jt * 16 + m;
#pragma unroll
      for (int r = 0; r < 4; ++r) {
        const float e    = exp2f(acc[jt][r] * 2.8853900817779268f);   // 2*log2(e)*x
        const float hval = 1.0f - 2.0f * __builtin_amdgcn_rcpf(1.0f + e);
        const int b = q * 4 + r;
        *(f16*)(nxt + (j >> 3) * 256 + b * 16 + (j & 7) * 2) = (f16)hval;
      }
    }
    __syncthreads();                 // all h writes visible (also drains prefetch)

    if constexpr (LAYER < 2) {       // one coalesced 16B store/thread: image copy to global
      char* gp = (char*)outbuf + (((size_t)(tile * 2 + slot) * TC + tl) << 13) + tid * 16;
      *(float4_t*)gp = *(const float4_t*)(nxt + tid * 16);
    }
  }

  // persist h (TC even -> final h image is buffer 0)
  *(float4_t*)((char*)st + tile * 8192 + tid * 16) = *(const float4_t*)(h_lds + tid * 16);
}

__global__ __launch_bounds__(512, 2)
void rnn_chunk_kernel(const float* __restrict__ x,
                      f16* bufA, f16* bufB,
                      const f16* __restrict__ wih0h, const f16* __restrict__ whh0h,
                      const f16* __restrict__ wih1h, const f16* __restrict__ whh1h,
                      const f16* __restrict__ wih2h, const f16* __restrict__ whh2h,
                      const float* __restrict__ biasc,
                      f16* st0, f16* st1, f16* st2, int k)
{
  __shared__ __align__(16) char smem[16384 + 24576];
  const int layer = blockIdx.x >> 5;
  const int tile  = blockIdx.x & 31;
  const int chunk = k - layer;
  if (chunk < 0 || chunk >= NCH) return;
  if (layer == 0)
    layer_body<0>(smem, chunk, tile, x, nullptr, wih0h, whh0h, biasc, bufA, st0);
  else if (layer == 1)
    layer_body<1>(smem, chunk, tile, nullptr, bufA, wih1h, whh1h, biasc, bufB, st1);
  else
    layer_body<2>(smem, chunk, tile, nullptr, bufB, wih2h, whh2h, biasc, nullptr, st2);
}

// one-time weight convert f32->f16 (row-major preserved) + bias combine
__global__ void prep_kernel(const float* __restrict__ wih0, const float* __restrict__ whh0,
                            const float* __restrict__ bih0, const float* __restrict__ bhh0,
                            const float* __restrict__ wih1, const float* __restrict__ whh1,
                            const float* __restrict__ bih1, const float* __restrict__ bhh1,
                            const float* __restrict__ wih2, const float* __restrict__ whh2,
                            const float* __restrict__ bih2, const float* __restrict__ bhh2,
                            f16* wih0h, f16* whh0h, f16* wih1h, f16* whh1h,
                            f16* wih2h, f16* whh2h, float* biasc)
{
  const int i = blockIdx.x * 256 + threadIdx.x;
  if      (i < 16384)  wih0h[i]          = (f16)wih0[i];
  else if (i < 81920)  whh0h[i - 16384]  = (f16)whh0[i - 16384];
  else if (i < 147456) wih1h[i - 81920]  = (f16)wih1[i - 81920];
  else if (i < 212992) whh1h[i - 147456] = (f16)whh1[i - 147456];
  else if (i < 278528) wih2h[i - 212992] = (f16)wih2[i - 212992];
  else if (i < 344064) whh2h[i - 278528] = (f16)whh2[i - 278528];
  else if (i < 344320) biasc[i - 344064]       = bih0[i - 344064] + bhh0[i - 344064];
  else if (i < 344576) biasc[256 + i - 344320] = bih1[i - 344320] + bhh1[i - 344320];
  else if (i < 344832) biasc[512 + i - 344576] = bih2[i - 344576] + bhh2[i - 344576];
}

__global__ void fc_kernel(const f16* __restrict__ st2, const float* __restrict__ w_fc,
                          const float* __restrict__ b_fc, float* __restrict__ outp) {
  const int b = blockIdx.x;            // 512
  const int lane = threadIdx.x;        // 64
  const int tile = b >> 4, bl = b & 15;
  const int j = lane * 4;              // 4 consecutive cols; contiguous 8B in image
  const char* hp = (const char*)st2 + tile * 8192 + (j >> 3) * 256 + bl * 16 + (j & 7) * 2;
  const half4_t hv = *(const half4_t*)hp;
  const float4_t w = *(const float4_t*)(w_fc + j);
  float s = (float)hv[0] * w[0] + (float)hv[1] * w[1] + (float)hv[2] * w[2] + (float)hv[3] * w[3];
#pragma unroll
  for (int off = 32; off > 0; off >>= 1) s += __shfl_down(s, off, 64);
  if (lane == 0) outp[b] = s + b_fc[0];
}

extern "C" void kernel_launch(void* const* d_in, const int* in_sizes, int n_in,
                              void* d_out, int out_size, void* d_ws, size_t ws_size,
                              hipStream_t stream) {
  const float* x     = (const float*)d_in[0];
  const float* w_ih0 = (const float*)d_in[1];
  const float* w_hh0 = (const float*)d_in[2];
  const float* b_ih0 = (const float*)d_in[3];
  const float* b_hh0 = (const float*)d_in[4];
  const float* w_ih1 = (const float*)d_in[5];
  const float* w_hh1 = (const float*)d_in[6];
  const float* b_ih1 = (const float*)d_in[7];
  const float* b_hh1 = (const float*)d_in[8];
  const float* w_ih2 = (const float*)d_in[9];
  const float* w_hh2 = (const float*)d_in[10];
  const float* b_ih2 = (const float*)d_in[11];
  const float* b_hh2 = (const float*)d_in[12];
  const float* w_fc  = (const float*)d_in[13];
  const float* b_fc  = (const float*)d_in[14];

  // ws layout, 35.0 MB total (round-3 proved ws_size >= 269,484,032):
  char* ws = (char*)d_ws;
  f16* bufA   = (f16*)(ws);                   // 16,777,216  L0->L1 ring (32 tiles x 2 slots x 32 x 8KB)
  f16* bufB   = (f16*)(ws + 16777216);        // 16,777,216  L1->L2 ring
  f16* st0    = (f16*)(ws + 33554432);        //    262,144  carried h, layer 0 (image)
  f16* st1    = (f16*)(ws + 33816576);        //    262,144
  f16* st2    = (f16*)(ws + 34078720);        //    262,144
  f16* wih0h  = (f16*)(ws + 34340864);        //     32,768
  f16* whh0h  = (f16*)(ws + 34373632);        //    131,072
  f16* wih1h  = (f16*)(ws + 34504704);        //    131,072
  f16* whh1h  = (f16*)(ws + 34635776);        //    131,072
  f16* wih2h  = (f16*)(ws + 34766848);        //    131,072
  f16* whh2h  = (f16*)(ws + 34897920);        //    131,072
  float* biasc = (float*)(ws + 35028992);     //      3,072

  prep_kernel<<<1347, 256, 0, stream>>>(w_ih0, w_hh0, b_ih0, b_hh0,
                                        w_ih1, w_hh1, b_ih1, b_hh1,
                                        w_ih2, w_hh2, b_ih2, b_hh2,
                                        wih0h, whh0h, wih1h, whh1h, wih2h, whh2h, biasc);
  // time-skewed layer pipeline: launch k runs L0@chunk k, L1@k-1, L2@k-2.
  // Kernel boundaries provide the producer->consumer ordering (no device sync needed).
  for (int k = 0; k < NCH + 2; ++k)
    rnn_chunk_kernel<<<96, 512, 0, stream>>>(x, bufA, bufB,
                                             wih0h, whh0h, wih1h, whh1h, wih2h, whh2h,
                                             biasc, st0, st1, st2, k);
  fc_kernel<<<512, 64, 0, stream>>>(st2, w_fc, b_fc, (float*)d_out);
}

// Round 6
// 1827.765 us; speedup vs baseline: 1.5896x; 1.0256x over previous
//
#include <hip/hip_runtime.h>
#include <cstdint>
#include <cstddef>

#define Tsz 512
#define TC  32          // steps per chunk
#define NCH 16          // Tsz / TC

typedef _Float16 f16;
typedef _Float16 half8_t __attribute__((ext_vector_type(8)));
typedef _Float16 half4_t __attribute__((ext_vector_type(4)));
typedef float float4_t __attribute__((ext_vector_type(4)));

__device__ __forceinline__ void async_ld16(const void* g, void* lds) {
  __builtin_amdgcn_global_load_lds(
      (const __attribute__((address_space(1))) void*)g,
      (__attribute__((address_space(3))) void*)lds, 16, 0, 0);
}
__device__ __forceinline__ float fast_exp2(float x) {
  float r;
  asm("v_exp_f32 %0, %1" : "=v"(r) : "v"(x));
  return r;
}

// Counted-waitcnt barriers (round-3-proven): do NOT drain vmcnt(0) each step.
#define BARRIER_VM(vm) asm volatile("s_waitcnt vmcnt(" #vm ") lgkmcnt(0)\n\ts_barrier" ::: "memory")
#define BARRIER_LG     asm volatile("s_waitcnt lgkmcnt(0)\n\ts_barrier" ::: "memory")

// One layer-chunk: TC steps of layer LAYER on one 16-row batch tile.
// 512 threads = 8 waves; wave owns 32 output cols (2 MFMA col-tiles).
// h double-buffered in LDS -> ONE barrier per step; counted vmcnt keeps
// prefetches (x regs / global_load_lds) and out-stores in flight across it.
// Cross-layer handoff at kernel-launch boundaries (proven-coherent).
template<int LAYER>
__device__ __forceinline__ void layer_body(
    char* const smem, const int chunk, const int tile,
    const float* __restrict__ x,     // LAYER==0 input
    const f16* inbuf,                // LAYER>=1 input ring (image layout)
    const f16* __restrict__ wih_h, const f16* __restrict__ whh_h,
    const float* __restrict__ biasc,
    f16* outbuf,                     // LAYER<2 output ring (image layout)
    f16* st)                         // per-layer carried h (image layout)
{
  constexpr int NIN = (LAYER == 0) ? 2 : 8;
  char* const h_lds = smem;          // 2 x 8192: [32 chunks][16 rows][16B] images
  char* const stage = smem + 16384;  // 3 x 8192 input ring (same image layout)

  const int tid  = threadIdx.x;
  const int lane = tid & 63;
  const int wave = tid >> 6;
  const int m    = lane & 15;
  const int q    = lane >> 4;
  const int lo   = m * 16;
  const int t0   = chunk * TC;
  const int slot = chunk & 1;        // ring slot for both in (this layer) & out

  // register-resident f16 weights (B-operand: B[k][n]=W[n][k], n=lane&15, k=q*8+i)
  half8_t whh[2][8], wih[2][NIN];
  float bias[2];
#pragma unroll
  for (int jt = 0; jt < 2; ++jt) {
    const int j = wave * 32 + jt * 16 + m;
    bias[jt] = biasc[LAYER * 256 + j];
#pragma unroll
    for (int c = 0; c < 8; ++c)
      whh[jt][c] = *(const half8_t*)(whh_h + j * 256 + c * 32 + q * 8);
#pragma unroll
    for (int c = 0; c < NIN; ++c)
      wih[jt][c] = *(const half8_t*)(wih_h + j * (NIN * 32) + c * 32 + q * 8);
  }

  // h_{t0-1}: zeros on chunk 0, else carried state (image copy)
  if (chunk == 0)
    *(float4_t*)(h_lds + tid * 16) = float4_t{0.f, 0.f, 0.f, 0.f};
  else
    *(float4_t*)(h_lds + tid * 16) = *(const float4_t*)((const char*)st + tile * 8192 + tid * 16);

  // input machinery
  float4_t xp[3][4];                 // LAYER0: 3-deep register ring of f32 x rows
  auto xload = [&](int t, float4_t* d) {
    const int tc = (t > Tsz - 1) ? (Tsz - 1) : t;
    const float* base = x + ((size_t)(tile * 16 + m) * Tsz + tc) * 64 + q * 8;
    d[0] = *(const float4_t*)base;        d[1] = *(const float4_t*)(base + 4);
    d[2] = *(const float4_t*)(base + 32); d[3] = *(const float4_t*)(base + 36);
  };
  auto issue_stage = [&](int tl, int sl) {  // 8KB image; wave w covers bytes [w*1024, +1024)
    const char* g = (const char*)inbuf + (((size_t)(tile * 2 + slot) * TC + tl) << 13)
                    + wave * 1024 + lane * 16;
    async_ld16(g, stage + sl * 8192 + wave * 1024);
  };

  if constexpr (LAYER == 0) {
    xload(t0, xp[0]); xload(t0 + 1, xp[1]); xload(t0 + 2, xp[2]);
    BARRIER_LG;                      // h image visible; x waits are compiler-managed
  } else {
    issue_stage(0, 0); issue_stage(1, 1);
    BARRIER_VM(2);                   // stage(0) landed (2 newest = stage(1) in flight)
  }

  for (int tl = 0; tl < TC; ++tl) {
    char* cur = h_lds + (tl & 1) * 8192;
    char* nxt = h_lds + ((tl + 1) & 1) * 8192;

    // A-fragments + prefetch next input
    half8_t xf[NIN];
    if constexpr (LAYER == 0) {
      const float4_t* xr = xp[tl % 3];
#pragma unroll
      for (int c = 0; c < 2; ++c)
#pragma unroll
        for (int u = 0; u < 8; ++u) xf[c][u] = (f16)xr[c * 2 + (u >> 2)][u & 3];
      xload(t0 + tl + 3, xp[tl % 3]);          // overwrite just-consumed slot
    } else {
      const char* sb = stage + (tl % 3) * 8192;
#pragma unroll
      for (int c = 0; c < 8; ++c) xf[c] = *(const half8_t*)(sb + (c * 4 + q) * 256 + lo);
      if (tl + 2 < TC) issue_stage(tl + 2, (tl + 2) % 3);   // slot consumed last step
    }
    half8_t hf[8];
#pragma unroll
    for (int c = 0; c < 8; ++c) hf[c] = *(const half8_t*)(cur + (c * 4 + q) * 256 + lo);

    // two independent MFMA chains per col-tile
    float4_t acc[2];
#pragma unroll
    for (int jt = 0; jt < 2; ++jt) {
      float4_t a0 = {bias[jt], bias[jt], bias[jt], bias[jt]};
      float4_t a1 = {0.f, 0.f, 0.f, 0.f};
#pragma unroll
      for (int c = 0; c < NIN; ++c)
        a0 = __builtin_amdgcn_mfma_f32_16x16x32_f16(xf[c], wih[jt][c], a0, 0, 0, 0);
#pragma unroll
      for (int c = 0; c < 8; ++c)
        a1 = __builtin_amdgcn_mfma_f32_16x16x32_f16(hf[c], whh[jt][c], a1, 0, 0, 0);
      acc[jt] = a0 + a1;
    }

    // epilogue: tanh -> h(t) image in nxt. C/D layout: col=lane&15, row=q*4+r.
    // tanh(x) = 1 - 2/(1+e^{2x}); raw v_exp_f32 (inf-safe at both ends).
#pragma unroll
    for (int jt = 0; jt < 2; ++jt) {
      const int j = wave * 32 + jt * 16 + m;
#pragma unroll
      for (int r = 0; r < 4; ++r) {
        const float e    = fast_exp2(acc[jt][r] * 2.8853900817779268f);   // 2*log2(e)*x
        const float hval = 1.0f - 2.0f * __builtin_amdgcn_rcpf(1.0f + e);
        const int b = q * 4 + r;
        *(f16*)(nxt + (j >> 3) * 256 + b * 16 + (j & 7) * 2) = (f16)hval;
      }
    }

    // ONE barrier per step. lgkm: h writes visible. vmcnt counted so stage
    // prefetch + out stores stay in flight (L0: x loads compiler-managed).
    if constexpr (LAYER == 0) BARRIER_LG;
    else if constexpr (LAYER == 1) BARRIER_VM(4);  // 2 stage(tl+2) + 2 store(tl-1) newer than stage(tl+1)
    else BARRIER_VM(2);                            // 2 stage(tl+2) newer than stage(tl+1)

    if constexpr (LAYER < 2) {       // coalesced image copy of h(t) to global ring
      char* gp = (char*)outbuf + (((size_t)(tile * 2 + slot) * TC + tl) << 13) + tid * 16;
      *(float4_t*)gp = *(const float4_t*)(nxt + tid * 16);
    }
  }

  // persist h (TC even -> final h image is buffer 0)
  *(float4_t*)((char*)st + tile * 8192 + tid * 16) = *(const float4_t*)(h_lds + tid * 16);
}

__global__ __launch_bounds__(512, 2)
void rnn_chunk_kernel(const float* __restrict__ x,
                      f16* bufA, f16* bufB,
                      const f16* __restrict__ wih0h, const f16* __restrict__ whh0h,
                      const f16* __restrict__ wih1h, const f16* __restrict__ whh1h,
                      const f16* __restrict__ wih2h, const f16* __restrict__ whh2h,
                      const float* __restrict__ biasc,
                      f16* st0, f16* st1, f16* st2, int k)
{
  __shared__ __align__(16) char smem[16384 + 24576];
  const int layer = blockIdx.x >> 5;
  const int tile  = blockIdx.x & 31;
  const int chunk = k - layer;
  if (chunk < 0 || chunk >= NCH) return;
  if (layer == 0)
    layer_body<0>(smem, chunk, tile, x, nullptr, wih0h, whh0h, biasc, bufA, st0);
  else if (layer == 1)
    layer_body<1>(smem, chunk, tile, nullptr, bufA, wih1h, whh1h, biasc, bufB, st1);
  else
    layer_body<2>(smem, chunk, tile, nullptr, bufB, wih2h, whh2h, biasc, nullptr, st2);
}

// one-time weight convert f32->f16 (row-major preserved) + bias combine
__global__ void prep_kernel(const float* __restrict__ wih0, const float* __restrict__ whh0,
                            const float* __restrict__ bih0, const float* __restrict__ bhh0,
                            const float* __restrict__ wih1, const float* __restrict__ whh1,
                            const float* __restrict__ bih1, const float* __restrict__ bhh1,
                            const float* __restrict__ wih2, const float* __restrict__ whh2,
                            const float* __restrict__ bih2, const float* __restrict__ bhh2,
                            f16* wih0h, f16* whh0h, f16* wih1h, f16* whh1h,
                            f16* wih2h, f16* whh2h, float* biasc)
{
  const int i = blockIdx.x * 256 + threadIdx.x;
  if      (i < 16384)  wih0h[i]          = (f16)wih0[i];
  else if (i < 81920)  whh0h[i - 16384]  = (f16)whh0[i - 16384];
  else if (i < 147456) wih1h[i - 81920]  = (f16)wih1[i - 81920];
  else if (i < 212992) whh1h[i - 147456] = (f16)whh1[i - 147456];
  else if (i < 278528) wih2h[i - 212992] = (f16)wih2[i - 212992];
  else if (i < 344064) whh2h[i - 278528] = (f16)whh2[i - 278528];
  else if (i < 344320) biasc[i - 344064]       = bih0[i - 344064] + bhh0[i - 344064];
  else if (i < 344576) biasc[256 + i - 344320] = bih1[i - 344320] + bhh1[i - 344320];
  else if (i < 344832) biasc[512 + i - 344576] = bih2[i - 344576] + bhh2[i - 344576];
}

__global__ void fc_kernel(const f16* __restrict__ st2, const float* __restrict__ w_fc,
                          const float* __restrict__ b_fc, float* __restrict__ outp) {
  const int b = blockIdx.x;            // 512
  const int lane = threadIdx.x;        // 64
  const int tile = b >> 4, bl = b & 15;
  const int j = lane * 4;              // 4 consecutive cols; contiguous 8B in image
  const char* hp = (const char*)st2 + tile * 8192 + (j >> 3) * 256 + bl * 16 + (j & 7) * 2;
  const half4_t hv = *(const half4_t*)hp;
  const float4_t w = *(const float4_t*)(w_fc + j);
  float s = (float)hv[0] * w[0] + (float)hv[1] * w[1] + (float)hv[2] * w[2] + (float)hv[3] * w[3];
#pragma unroll
  for (int off = 32; off > 0; off >>= 1) s += __shfl_down(s, off, 64);
  if (lane == 0) outp[b] = s + b_fc[0];
}

extern "C" void kernel_launch(void* const* d_in, const int* in_sizes, int n_in,
                              void* d_out, int out_size, void* d_ws, size_t ws_size,
                              hipStream_t stream) {
  const float* x     = (const float*)d_in[0];
  const float* w_ih0 = (const float*)d_in[1];
  const float* w_hh0 = (const float*)d_in[2];
  const float* b_ih0 = (const float*)d_in[3];
  const float* b_hh0 = (const float*)d_in[4];
  const float* w_ih1 = (const float*)d_in[5];
  const float* w_hh1 = (const float*)d_in[6];
  const float* b_ih1 = (const float*)d_in[7];
  const float* b_hh1 = (const float*)d_in[8];
  const float* w_ih2 = (const float*)d_in[9];
  const float* w_hh2 = (const float*)d_in[10];
  const float* b_ih2 = (const float*)d_in[11];
  const float* b_hh2 = (const float*)d_in[12];
  const float* w_fc  = (const float*)d_in[13];
  const float* b_fc  = (const float*)d_in[14];

  // ws layout, 35.0 MB total (round-3 proved ws_size >= 269,484,032):
  char* ws = (char*)d_ws;
  f16* bufA   = (f16*)(ws);                   // 16,777,216  L0->L1 ring (32 tiles x 2 slots x 32 x 8KB)
  f16* bufB   = (f16*)(ws + 16777216);        // 16,777,216  L1->L2 ring
  f16* st0    = (f16*)(ws + 33554432);        //    262,144  carried h, layer 0 (image)
  f16* st1    = (f16*)(ws + 33816576);        //    262,144
  f16* st2    = (f16*)(ws + 34078720);        //    262,144
  f16* wih0h  = (f16*)(ws + 34340864);        //     32,768
  f16* whh0h  = (f16*)(ws + 34373632);        //    131,072
  f16* wih1h  = (f16*)(ws + 34504704);        //    131,072
  f16* whh1h  = (f16*)(ws + 34635776);        //    131,072
  f16* wih2h  = (f16*)(ws + 34766848);        //    131,072
  f16* whh2h  = (f16*)(ws + 34897920);        //    131,072
  float* biasc = (float*)(ws + 35028992);     //      3,072

  prep_kernel<<<1347, 256, 0, stream>>>(w_ih0, w_hh0, b_ih0, b_hh0,
                                        w_ih1, w_hh1, b_ih1, b_hh1,
                                        w_ih2, w_hh2, b_ih2, b_hh2,
                                        wih0h, whh0h, wih1h, whh1h, wih2h, whh2h, biasc);
  // time-skewed layer pipeline: launch k runs L0@chunk k, L1@k-1, L2@k-2.
  // Kernel boundaries provide the producer->consumer ordering (no device sync needed).
  for (int k = 0; k < NCH + 2; ++k)
    rnn_chunk_kernel<<<96, 512, 0, stream>>>(x, bufA, bufB,
                                             wih0h, whh0h, wih1h, whh1h, wih2h, whh2h,
                                             biasc, st0, st1, st2, k);
  fc_kernel<<<512, 64, 0, stream>>>(st2, w_fc, b_fc, (float*)d_out);
}

// Round 7
// 1069.008 us; speedup vs baseline: 2.7179x; 1.7098x over previous
//
#include <hip/hip_runtime.h>
#include <cstdint>
#include <cstddef>

#define Tsz 512
#define TC  32          // steps per chunk
#define NCH 16          // Tsz / TC

typedef _Float16 f16;
typedef _Float16 half8_t __attribute__((ext_vector_type(8)));
typedef _Float16 half4_t __attribute__((ext_vector_type(4)));
typedef float float4_t __attribute__((ext_vector_type(4)));

__device__ __forceinline__ void async_ld16(const void* g, void* lds) {
  __builtin_amdgcn_global_load_lds(
      (const __attribute__((address_space(1))) void*)g,
      (__attribute__((address_space(3))) void*)lds, 16, 0, 0);
}
__device__ __forceinline__ float fast_exp2(float x) {
  float r;
  asm("v_exp_f32 %0, %1" : "=v"(r) : "v"(x));
  return r;
}
// Opaque pin: value becomes asm-defined -> compiler cannot rematerialize it
// by re-loading from memory inside the loop. THE fix for VGPR_Count=116.
__device__ __forceinline__ void pin(half8_t& v) { asm("" : "+v"(v)); }

// Counted-waitcnt barriers: do NOT drain vmcnt(0) each step.
#define BARRIER_VM(vm) asm volatile("s_waitcnt vmcnt(" #vm ") lgkmcnt(0)\n\ts_barrier" ::: "memory")
#define BARRIER_LG     asm volatile("s_waitcnt lgkmcnt(0)\n\ts_barrier" ::: "memory")

// One layer-chunk: TC steps of layer LAYER on one 16-row batch tile.
// 512 threads = 8 waves; wave owns 32 output cols (2 MFMA col-tiles).
// Weights truly register-resident (pinned). h double-buffered in LDS ->
// ONE barrier/step; stage ring 4-deep, x register ring 2-deep; loop
// unrolled x4 so all ring indices are compile-time (no scratch demotion).
template<int LAYER>
__device__ __forceinline__ void layer_body(
    char* const smem, const int chunk, const int tile,
    const float* __restrict__ x,     // LAYER==0 input
    const f16* inbuf,                // LAYER>=1 input ring (image layout)
    const f16* __restrict__ wih_h, const f16* __restrict__ whh_h,
    const float* __restrict__ biasc,
    f16* outbuf,                     // LAYER<2 output ring (image layout)
    f16* st)                         // per-layer carried h (image layout)
{
  constexpr int NIN = (LAYER == 0) ? 2 : 8;
  char* const h_lds = smem;          // 2 x 8192: [32 chunks][16 rows][16B] images
  char* const stage = smem + 16384;  // 4 x 8192 input ring (same image layout)

  const int tid  = threadIdx.x;
  const int lane = tid & 63;
  const int wave = tid >> 6;
  const int m    = lane & 15;
  const int q    = lane >> 4;
  const int lo   = m * 16;
  const int t0   = chunk * TC;
  const int slot = chunk & 1;        // global ring slot for in/out bufs

  // one-time weight load (B-operand: B[k][n]=W[n][k], n=lane&15, k=q*8+i), then PIN
  half8_t whh[2][8], wih[2][NIN];
  float bias[2];
#pragma unroll
  for (int jt = 0; jt < 2; ++jt) {
    const int j = wave * 32 + jt * 16 + m;
    bias[jt] = biasc[LAYER * 256 + j];
#pragma unroll
    for (int c = 0; c < 8; ++c)
      whh[jt][c] = *(const half8_t*)(whh_h + j * 256 + c * 32 + q * 8);
#pragma unroll
    for (int c = 0; c < NIN; ++c)
      wih[jt][c] = *(const half8_t*)(wih_h + j * (NIN * 32) + c * 32 + q * 8);
  }
#pragma unroll
  for (int jt = 0; jt < 2; ++jt) {
#pragma unroll
    for (int c = 0; c < 8; ++c) pin(whh[jt][c]);
#pragma unroll
    for (int c = 0; c < NIN; ++c) pin(wih[jt][c]);
  }

  // h_{t0-1}: zeros on chunk 0, else carried state (image copy)
  if (chunk == 0)
    *(float4_t*)(h_lds + tid * 16) = float4_t{0.f, 0.f, 0.f, 0.f};
  else
    *(float4_t*)(h_lds + tid * 16) = *(const float4_t*)((const char*)st + tile * 8192 + tid * 16);

  // input machinery
  float4_t xp[2][4];                 // LAYER0: 2-deep register ping-pong of f32 x rows
  auto xload = [&](int t, float4_t* d) {
    const int tc = (t > Tsz - 1) ? (Tsz - 1) : t;
    const float* base = x + ((size_t)(tile * 16 + m) * Tsz + tc) * 64 + q * 8;
    d[0] = *(const float4_t*)base;        d[1] = *(const float4_t*)(base + 4);
    d[2] = *(const float4_t*)(base + 32); d[3] = *(const float4_t*)(base + 36);
  };
  auto issue_stage = [&](int tl, int sl) {  // 8KB image; wave w covers bytes [w*1024, +1024)
    const int tn = (tl > TC - 1) ? (TC - 1) : tl;
    const char* g = (const char*)inbuf + (((size_t)(tile * 2 + slot) * TC + tn) << 13)
                    + wave * 1024 + lane * 16;
    async_ld16(g, stage + sl * 8192 + wave * 1024);
  };

  if constexpr (LAYER == 0) {
    xload(t0, xp[0]); xload(t0 + 1, xp[1]);
    BARRIER_LG;                      // h image visible; x waits compiler-managed
  } else {
    issue_stage(0, 0); issue_stage(1, 1);
    BARRIER_VM(1);                   // stage(0) landed (1 newest = stage(1) in flight)
  }

#pragma unroll 4
  for (int tl = 0; tl < TC; ++tl) {
    char* cur = h_lds + (tl & 1) * 8192;
    char* nxt = h_lds + ((tl + 1) & 1) * 8192;

    // A-fragments + prefetch next input (dist 2; consume-then-refill same slot)
    half8_t xf[NIN];
    if constexpr (LAYER == 0) {
      const float4_t* xr = xp[tl & 1];
#pragma unroll
      for (int c = 0; c < 2; ++c)
#pragma unroll
        for (int u = 0; u < 8; ++u) xf[c][u] = (f16)xr[c * 2 + (u >> 2)][u & 3];
      xload(t0 + tl + 2, xp[tl & 1]);          // refill just-consumed slot
    } else {
      const char* sb = stage + (tl & 3) * 8192;
#pragma unroll
      for (int c = 0; c < 8; ++c) xf[c] = *(const half8_t*)(sb + (c * 4 + q) * 256 + lo);
      issue_stage(tl + 2, (tl + 2) & 3);       // slot last read 2 steps ago -> race-free
    }
    half8_t hf[8];
#pragma unroll
    for (int c = 0; c < 8; ++c) hf[c] = *(const half8_t*)(cur + (c * 4 + q) * 256 + lo);

    // two independent MFMA chains per col-tile
    float4_t acc[2];
#pragma unroll
    for (int jt = 0; jt < 2; ++jt) {
      float4_t a0 = {bias[jt], bias[jt], bias[jt], bias[jt]};
      float4_t a1 = {0.f, 0.f, 0.f, 0.f};
#pragma unroll
      for (int c = 0; c < NIN; ++c)
        a0 = __builtin_amdgcn_mfma_f32_16x16x32_f16(xf[c], wih[jt][c], a0, 0, 0, 0);
#pragma unroll
      for (int c = 0; c < 8; ++c)
        a1 = __builtin_amdgcn_mfma_f32_16x16x32_f16(hf[c], whh[jt][c], a1, 0, 0, 0);
      acc[jt] = a0 + a1;
    }

    // epilogue: tanh -> h(t) image in nxt. C/D layout: col=lane&15, row=q*4+r.
    // tanh(x) = 1 - 2/(1+e^{2x}); raw v_exp_f32 (inf-safe at both ends).
#pragma unroll
    for (int jt = 0; jt < 2; ++jt) {
      const int j = wave * 32 + jt * 16 + m;
#pragma unroll
      for (int r = 0; r < 4; ++r) {
        const float e    = fast_exp2(acc[jt][r] * 2.8853900817779268f);   // 2*log2(e)*x
        const float hval = 1.0f - 2.0f * __builtin_amdgcn_rcpf(1.0f + e);
        const int b = q * 4 + r;
        *(f16*)(nxt + (j >> 3) * 256 + b * 16 + (j & 7) * 2) = (f16)hval;
      }
    }

    // ONE barrier per step. lgkm: h writes visible. vmcnt(1): stage(tl+1)
    // landed (only stage(tl+2) may fly; prior-step store had a full step to retire).
    if constexpr (LAYER == 0) BARRIER_LG;
    else BARRIER_VM(1);

    if constexpr (LAYER < 2) {       // coalesced image copy of h(t) to global ring
      char* gp = (char*)outbuf + (((size_t)(tile * 2 + slot) * TC + tl) << 13) + tid * 16;
      *(float4_t*)gp = *(const float4_t*)(nxt + tid * 16);
    }
  }

  // persist h (TC even -> final h image is buffer 0)
  *(float4_t*)((char*)st + tile * 8192 + tid * 16) = *(const float4_t*)(h_lds + tid * 16);
}

__global__ __launch_bounds__(512, 1)
void rnn_chunk_kernel(const float* __restrict__ x,
                      f16* bufA, f16* bufB,
                      const f16* __restrict__ wih0h, const f16* __restrict__ whh0h,
                      const f16* __restrict__ wih1h, const f16* __restrict__ whh1h,
                      const f16* __restrict__ wih2h, const f16* __restrict__ whh2h,
                      const float* __restrict__ biasc,
                      f16* st0, f16* st1, f16* st2, int k)
{
  __shared__ __align__(16) char smem[16384 + 32768];
  const int layer = blockIdx.x >> 5;
  const int tile  = blockIdx.x & 31;
  const int chunk = k - layer;
  if (chunk < 0 || chunk >= NCH) return;
  if (layer == 0)
    layer_body<0>(smem, chunk, tile, x, nullptr, wih0h, whh0h, biasc, bufA, st0);
  else if (layer == 1)
    layer_body<1>(smem, chunk, tile, nullptr, bufA, wih1h, whh1h, biasc, bufB, st1);
  else
    layer_body<2>(smem, chunk, tile, nullptr, bufB, wih2h, whh2h, biasc, nullptr, st2);
}

// one-time weight convert f32->f16 (row-major preserved) + bias combine
__global__ void prep_kernel(const float* __restrict__ wih0, const float* __restrict__ whh0,
                            const float* __restrict__ bih0, const float* __restrict__ bhh0,
                            const float* __restrict__ wih1, const float* __restrict__ whh1,
                            const float* __restrict__ bih1, const float* __restrict__ bhh1,
                            const float* __restrict__ wih2, const float* __restrict__ whh2,
                            const float* __restrict__ bih2, const float* __restrict__ bhh2,
                            f16* wih0h, f16* whh0h, f16* wih1h, f16* whh1h,
                            f16* wih2h, f16* whh2h, float* biasc)
{
  const int i = blockIdx.x * 256 + threadIdx.x;
  if      (i < 16384)  wih0h[i]          = (f16)wih0[i];
  else if (i < 81920)  whh0h[i - 16384]  = (f16)whh0[i - 16384];
  else if (i < 147456) wih1h[i - 81920]  = (f16)wih1[i - 81920];
  else if (i < 212992) whh1h[i - 147456] = (f16)whh1[i - 147456];
  else if (i < 278528) wih2h[i - 212992] = (f16)wih2[i - 212992];
  else if (i < 344064) whh2h[i - 278528] = (f16)whh2[i - 278528];
  else if (i < 344320) biasc[i - 344064]       = bih0[i - 344064] + bhh0[i - 344064];
  else if (i < 344576) biasc[256 + i - 344320] = bih1[i - 344320] + bhh1[i - 344320];
  else if (i < 344832) biasc[512 + i - 344576] = bih2[i - 344576] + bhh2[i - 344576];
}

__global__ void fc_kernel(const f16* __restrict__ st2, const float* __restrict__ w_fc,
                          const float* __restrict__ b_fc, float* __restrict__ outp) {
  const int b = blockIdx.x;            // 512
  const int lane = threadIdx.x;        // 64
  const int tile = b >> 4, bl = b & 15;
  const int j = lane * 4;              // 4 consecutive cols; contiguous 8B in image
  const char* hp = (const char*)st2 + tile * 8192 + (j >> 3) * 256 + bl * 16 + (j & 7) * 2;
  const half4_t hv = *(const half4_t*)hp;
  const float4_t w = *(const float4_t*)(w_fc + j);
  float s = (float)hv[0] * w[0] + (float)hv[1] * w[1] + (float)hv[2] * w[2] + (float)hv[3] * w[3];
#pragma unroll
  for (int off = 32; off > 0; off >>= 1) s += __shfl_down(s, off, 64);
  if (lane == 0) outp[b] = s + b_fc[0];
}

extern "C" void kernel_launch(void* const* d_in, const int* in_sizes, int n_in,
                              void* d_out, int out_size, void* d_ws, size_t ws_size,
                              hipStream_t stream) {
  const float* x     = (const float*)d_in[0];
  const float* w_ih0 = (const float*)d_in[1];
  const float* w_hh0 = (const float*)d_in[2];
  const float* b_ih0 = (const float*)d_in[3];
  const float* b_hh0 = (const float*)d_in[4];
  const float* w_ih1 = (const float*)d_in[5];
  const float* w_hh1 = (const float*)d_in[6];
  const float* b_ih1 = (const float*)d_in[7];
  const float* b_hh1 = (const float*)d_in[8];
  const float* w_ih2 = (const float*)d_in[9];
  const float* w_hh2 = (const float*)d_in[10];
  const float* b_ih2 = (const float*)d_in[11];
  const float* b_hh2 = (const float*)d_in[12];
  const float* w_fc  = (const float*)d_in[13];
  const float* b_fc  = (const float*)d_in[14];

  // ws layout, 35.0 MB total (round-3 proved ws_size >= 269,484,032):
  char* ws = (char*)d_ws;
  f16* bufA   = (f16*)(ws);                   // 16,777,216  L0->L1 ring (32 tiles x 2 slots x 32 x 8KB)
  f16* bufB   = (f16*)(ws + 16777216);        // 16,777,216  L1->L2 ring
  f16* st0    = (f16*)(ws + 33554432);        //    262,144  carried h, layer 0 (image)
  f16* st1    = (f16*)(ws + 33816576);        //    262,144
  f16* st2    = (f16*)(ws + 34078720);        //    262,144
  f16* wih0h  = (f16*)(ws + 34340864);        //     32,768
  f16* whh0h  = (f16*)(ws + 34373632);        //    131,072
  f16* wih1h  = (f16*)(ws + 34504704);        //    131,072
  f16* whh1h  = (f16*)(ws + 34635776);        //    131,072
  f16* wih2h  = (f16*)(ws + 34766848);        //    131,072
  f16* whh2h  = (f16*)(ws + 34897920);        //    131,072
  float* biasc = (float*)(ws + 35028992);     //      3,072

  prep_kernel<<<1347, 256, 0, stream>>>(w_ih0, w_hh0, b_ih0, b_hh0,
                                        w_ih1, w_hh1, b_ih1, b_hh1,
                                        w_ih2, w_hh2, b_ih2, b_hh2,
                                        wih0h, whh0h, wih1h, whh1h, wih2h, whh2h, biasc);
  // time-skewed layer pipeline: launch k runs L0@chunk k, L1@k-1, L2@k-2.
  // Kernel boundaries provide the producer->consumer ordering.
  for (int k = 0; k < NCH + 2; ++k)
    rnn_chunk_kernel<<<96, 512, 0, stream>>>(x, bufA, bufB,
                                             wih0h, whh0h, wih1h, whh1h, wih2h, whh2h,
                                             biasc, st0, st1, st2, k);
  fc_kernel<<<512, 64, 0, stream>>>(st2, w_fc, b_fc, (float*)d_out);
}